// Round 1
// baseline (190.010 us; speedup 1.0000x reference)
//
#include <hip/hip_runtime.h>
#include <cstdint>

#define Bq 4
#define Lq 4096
#define Hq 256
#define NHq 8
#define Tq 64
#define WINq 16
#define Dq 32
#define NSLOTS 33
#define NEG_SLOPE 5.0f
#define MASK_FILL -1e12f
#define TLq 64         // l-tile for k_attn
#define MB 16          // rows per block for MFMA GEMMs (1024 blocks -> 4/CU)

typedef __attribute__((ext_vector_type(8))) short short8;
typedef __attribute__((ext_vector_type(4))) float f32x4;

__device__ __forceinline__ float leaky(float x) { return x >= 0.f ? x : NEG_SLOPE * x; }

__device__ __forceinline__ uint16_t f2bf(float x) {   // RNE f32->bf16 bits
    uint32_t u = __float_as_uint(x);
    uint32_t r = (u + 0x7fffu + ((u >> 16) & 1u)) >> 16;
    return (uint16_t)r;
}
__device__ __forceinline__ float bf2f(uint16_t h) {
    return __uint_as_float(((uint32_t)h) << 16);
}

// ------- merged prep: blocks 0..127 pack Wc/Wo; blocks 128..383 do types -------
// W pack: dst[fragi*512 + l*8 + j] = W[kc*32+(l>>4)*8+j][nt*16+(l&15)], fragi=nt*8+kc
__global__ void k_prep(const float* __restrict__ Wc, const float* __restrict__ Wo,
                       uint16_t* __restrict__ pc_hi, uint16_t* __restrict__ pc_lo,
                       uint16_t* __restrict__ po_hi, uint16_t* __restrict__ po_lo,
                       const float* __restrict__ types, const float* __restrict__ Wt,
                       const float* __restrict__ bt, const float* __restrict__ down,
                       float* __restrict__ types_h, float* __restrict__ types_hT,
                       float* __restrict__ down_t) {
    __shared__ float sin[Hq];
    __shared__ float outr[Hq];
    if (blockIdx.x < 128) {
        int wsel = blockIdx.x >> 6;
        int blk = blockIdx.x & 63;
        const float* W = wsel ? Wo : Wc;
        uint16_t* ph = wsel ? po_hi : pc_hi;
        uint16_t* pl = wsel ? po_lo : pc_lo;
        int base = blk * 1024;
        for (int idx = base + threadIdx.x; idx < base + 1024; idx += 256) {
            int j = idx & 7, l = (idx >> 3) & 63, fragi = idx >> 9;
            int kc = fragi & 7, nt = fragi >> 3;
            int k = kc * 32 + (l >> 4) * 8 + j;
            int c = nt * 16 + (l & 15);
            float x = W[k * Hq + c];
            uint16_t h = f2bf(x);
            ph[idx] = h;
            pl[idx] = f2bf(x - bf2f(h));
        }
        return;
    }
    // ---- types projection + down_t + transposed copy ----
    int row = blockIdx.x - 128;    // b*T + t
    int h = threadIdx.x;
    int b = row >> 6, t = row & 63;
    sin[h] = types[(size_t)row * Hq + h];
    __syncthreads();
    float acc = bt[h];
    for (int k = 0; k < Hq; k += 4) {
        float4 iv = *(const float4*)&sin[k];
        acc = fmaf(iv.x, Wt[(k + 0) * Hq + h], acc);
        acc = fmaf(iv.y, Wt[(k + 1) * Hq + h], acc);
        acc = fmaf(iv.z, Wt[(k + 2) * Hq + h], acc);
        acc = fmaf(iv.w, Wt[(k + 3) * Hq + h], acc);
    }
    types_h[(size_t)row * Hq + h] = acc;
    types_hT[(size_t)(b * Hq + h) * Tq + t] = acc;   // [b][n][d][t]
    outr[h] = acc;
    __syncthreads();
    if (h < NHq) {
        float s = 0.f;
        for (int d = 0; d < Dq; ++d) s += outr[h * Dq + d] * down[h * Dq + d];
        down_t[(b * NHq + h) * Tq + t] = s;
    }
}

// ---------------- context projection via MFMA (bf16 hi/lo split) ----------------
// MB=16 rows/block, 4 waves; wave w owns col-tiles nt0=4w..4w+3 (A-tile shared)
#define APAD 264       // bf16 row stride for A tiles
#define OPAD 258       // f32 row stride for output staging
__global__ void __launch_bounds__(256) k_ctx(
        const float* __restrict__ ctx,
        const uint16_t* __restrict__ wp_hi, const uint16_t* __restrict__ wp_lo,
        const float* __restrict__ bc, const float* __restrict__ upon,
        const float* __restrict__ down,
        float* __restrict__ ctx_hT, float* __restrict__ uq,
        float* __restrict__ dsv) {
    int row0 = blockIdx.x * MB;
    int b = row0 >> 12, l0 = row0 & (Lq - 1);
    int tid = threadIdx.x;
    int w = tid >> 6, l = tid & 63;
    __shared__ __align__(16) char smem_raw[MB * APAD * 4];   // 16.9 KB
    uint16_t* a_hi = (uint16_t*)smem_raw;            // [16][APAD]
    uint16_t* a_lo = a_hi + MB * APAD;
    float* outb = (float*)smem_raw;                  // reused: [16][OPAD]

    // stage + split rows (16*64 = 1024 float4, 4/thread)
    {
        const float4* src = (const float4*)(ctx + (size_t)row0 * Hq);
#pragma unroll
        for (int j = 0; j < 4; ++j) {
            int f = tid + j * 256;
            int r = f >> 6, cg = f & 63;
            float4 v = src[f];
            uint16_t h0 = f2bf(v.x), h1 = f2bf(v.y), h2 = f2bf(v.z), h3 = f2bf(v.w);
            ushort4 hh = {h0, h1, h2, h3};
            ushort4 ll = {f2bf(v.x - bf2f(h0)), f2bf(v.y - bf2f(h1)),
                          f2bf(v.z - bf2f(h2)), f2bf(v.w - bf2f(h3))};
            *(ushort4*)&a_hi[r * APAD + cg * 4] = hh;
            *(ushort4*)&a_lo[r * APAD + cg * 4] = ll;
        }
    }
    __syncthreads();

    int nt0 = w * 4;               // wave col-tile base
    int m = l & 15, quad = l >> 4;
    f32x4 acc[4];
#pragma unroll
    for (int t = 0; t < 4; ++t) acc[t] = (f32x4){0.f, 0.f, 0.f, 0.f};
#pragma unroll
    for (int kc = 0; kc < 8; ++kc) {
        short8 ah = *(const short8*)&a_hi[m * APAD + kc * 32 + quad * 8];
        short8 al = *(const short8*)&a_lo[m * APAD + kc * 32 + quad * 8];
#pragma unroll
        for (int t = 0; t < 4; ++t) {
            int fragi = (nt0 + t) * 8 + kc;
            short8 wh = *(const short8*)&wp_hi[fragi * 512 + l * 8];
            short8 wl = *(const short8*)&wp_lo[fragi * 512 + l * 8];
            acc[t] = __builtin_amdgcn_mfma_f32_16x16x32_bf16(ah, wh, acc[t], 0, 0, 0);
            acc[t] = __builtin_amdgcn_mfma_f32_16x16x32_bf16(ah, wl, acc[t], 0, 0, 0);
            acc[t] = __builtin_amdgcn_mfma_f32_16x16x32_bf16(al, wh, acc[t], 0, 0, 0);
        }
    }
    __syncthreads();   // all a_hi/a_lo reads done; reuse smem as outb

    // write C (+bias) to LDS staging (row=quad*4+r, col=(nt0+t)*16+m)
#pragma unroll
    for (int t = 0; t < 4; ++t) {
        int col = (nt0 + t) * 16 + m;
        float bv = bc[col];
#pragma unroll
        for (int r = 0; r < 4; ++r)
            outb[(quad * 4 + r) * OPAD + col] = acc[t][r] + bv;
    }
    __syncthreads();

    // uq / dsv: threads 0..127 -> (r, n)
    if (tid < MB * NHq) {
        int r = tid >> 3, n = tid & 7;
        float su = 0.f, sd = 0.f;
        for (int d = 0; d < Dq; ++d) {
            float v = outb[r * OPAD + n * Dq + d];
            su += v * upon[n * Dq + d];
            sd += v * down[n * Dq + d];
        }
        uq[(b * NHq + n) * Lq + l0 + r] = su;
        dsv[(b * NHq + n) * Lq + l0 + r] = sd;
    }
    // transposed store: thread tid owns channel tid, writes 16 l's
    {
        float* dst = ctx_hT + (size_t)(b * Hq + tid) * Lq + l0;
#pragma unroll
        for (int j = 0; j < MB / 4; ++j) {
            float4 o;
            o.x = outb[(4 * j + 0) * OPAD + tid];
            o.y = outb[(4 * j + 1) * OPAD + tid];
            o.z = outb[(4 * j + 2) * OPAD + tid];
            o.w = outb[(4 * j + 3) * OPAD + tid];
            ((float4*)dst)[j] = o;
        }
    }
}

// ---------------- attention: tiled (b, n, 64 l's) per block ----------------
// R10: LDS 50.2KB -> 32.6KB (drop cr_s via quad shuffles, drop tts_s by
// reading st types from tts2_s rows). 3 -> 5 blocks/CU.
__global__ void __launch_bounds__(256, 5) k_attn(
        const float* __restrict__ ctx_hT, const float* __restrict__ types_h,
        const float* __restrict__ types_hT, const float* __restrict__ cross,
        const float* __restrict__ uq, const float* __restrict__ dsv,
        const float* __restrict__ dt, const unsigned char* __restrict__ maskp,
        float* __restrict__ update) {
    int blk = blockIdx.x;
    int lt = blk & 63, n = (blk >> 6) & 7, b = blk >> 9;
    int l0 = lt * TLq;
    int tid = threadIdx.x;
    int ls = tid >> 2;
    int q  = tid & 3;
    int pl = l0 + ls;
    bool mask_b8 = (maskp[1] != 0);

    __shared__ float chx_s[32 * 97];          // 12416 B
    __shared__ float crs_s[32 * 36];          //  4608 B
    __shared__ float dots_s[64 * 19];         //  4864 B
    __shared__ float tts2_s[64 * 36 + 16];    //  9280 B
    __shared__ float uqe[96], dsve[96], maskf[96], dts[64];   // 1408 B
    // total: 32576 B -> 5 blocks/CU

    {
        int d = tid >> 3, k = tid & 7;
        const float* grow = ctx_hT + ((size_t)(b * NHq + n) * Dq + d) * Lq;
        float* lrow = &chx_s[d * 97 + k * 12];
        if (l0 >= 16 && l0 <= Lq - 80) {
            const float4* g = (const float4*)(grow + (l0 - 16) + k * 12);
            float4 v0 = g[0], v1 = g[1], v2 = g[2];
            lrow[0] = v0.x; lrow[1] = v0.y; lrow[2]  = v0.z; lrow[3]  = v0.w;
            lrow[4] = v1.x; lrow[5] = v1.y; lrow[6]  = v1.z; lrow[7]  = v1.w;
            lrow[8] = v2.x; lrow[9] = v2.y; lrow[10] = v2.z; lrow[11] = v2.w;
        } else {
#pragma unroll
            for (int m = 0; m < 12; ++m) {
                int gl = l0 - 16 + k * 12 + m;
                int glw = (gl < 0) ? gl + Lq : ((gl >= Lq) ? gl - Lq : gl);
                lrow[m] = grow[glw];
            }
        }
    }
    {
        float4 v = ((const float4*)(cross + n * (Dq * Dq)))[tid];
        float* p = &crs_s[(tid >> 3) * 36 + (tid & 7) * 4];
        p[0] = v.x; p[1] = v.y; p[2] = v.z; p[3] = v.w;
    }
    {
        int t = tid >> 2, c4 = tid & 3;
        const float4* src = (const float4*)(types_h + (size_t)(b * Tq + t) * Hq
                                            + n * Dq + 8 * c4);
        float* p = &tts2_s[t * 36 + 4 * (t >> 4) + 8 * c4];
        ((float4*)p)[0] = src[0];
        ((float4*)p)[1] = src[1];
    }
    if (tid < 96) {
        int gl = l0 - 16 + tid;
        int glw = (gl < 0) ? gl + Lq : ((gl >= Lq) ? gl - Lq : gl);
        uqe[tid] = uq[(b * NHq + n) * Lq + glw];
        unsigned char mb = mask_b8 ? maskp[b * Lq + glw]
                                   : maskp[(size_t)(b * Lq + glw) * 4];
        maskf[tid] = mb ? 1.f : 0.f;
    } else if (tid < 192) {
        int j = tid - 96;
        int gl = l0 - 16 + j;
        int glw = (gl < 0) ? gl + Lq : ((gl >= Lq) ? gl - Lq : gl);
        dsve[j] = dsv[(b * NHq + n) * Lq + glw];
    } else {
        dts[tid - 192] = dt[(b * NHq + n) * Tq + (tid - 192)];
    }
    __syncthreads();

    // cr = ctx_h[l] . cross  — quad thread q owns cr[8q..8q+7], kept in regs
    float a[8];
#pragma unroll
    for (int ii = 0; ii < 8; ++ii) a[ii] = 0.f;
#pragma unroll 2
    for (int d = 0; d < Dq; ++d) {
        float chv = chx_s[d * 97 + ls + 16];
        const float4* cp = (const float4*)(&crs_s[d * 36 + 8 * q]);
        float4 c0 = cp[0], c1 = cp[1];
        a[0] = fmaf(chv, c0.x, a[0]); a[1] = fmaf(chv, c0.y, a[1]);
        a[2] = fmaf(chv, c0.z, a[2]); a[3] = fmaf(chv, c0.w, a[3]);
        a[4] = fmaf(chv, c1.x, a[4]); a[5] = fmaf(chv, c1.y, a[5]);
        a[6] = fmaf(chv, c1.z, a[6]); a[7] = fmaf(chv, c1.w, a[7]);
    }

    // prod_self dots: each thread contributes its 8 cr components
    float dot_self;
    {
#pragma unroll
        for (int u = 0; u < 17; ++u) {
            float acc = 0.f;
#pragma unroll
            for (int k = 0; k < 8; ++k)
                acc = fmaf(a[k], chx_s[(8 * q + k) * 97 + ls + 16 + u], acc);
            acc += __shfl_xor(acc, 1);
            acc += __shfl_xor(acc, 2);
            if (u == 0) dot_self = acc;
            else if (q == 0) dots_s[ls * 19 + u] = acc;
        }
    }

    float uq_l = uqe[ls + 16];
    float dsv_l = dsve[ls + 16];
    float cmask = maskf[ls + 16];

    int tb = 16 * q;
    float st[16];
#pragma unroll
    for (int j = 0; j < 16; ++j) st[j] = 0.f;
    // st[j] = cr . types_h[tb+j]; cr gathered from quad via width-4 shuffles,
    // 16 components at a time (keeps VGPR pressure low)
#pragma unroll
    for (int half = 0; half < 2; ++half) {
        float crf[16];
#pragma unroll
        for (int k = 0; k < 16; ++k)
            crf[k] = __shfl(a[k & 7], 2 * half + (k >> 3), 4);
#pragma unroll 4
        for (int j = 0; j < 16; ++j) {
            const float4* rp =
                (const float4*)&tts2_s[(tb + j) * 36 + 4 * q + 16 * half];
            float4 v0 = rp[0], v1 = rp[1], v2 = rp[2], v3 = rp[3];
            st[j] = fmaf(crf[0],  v0.x, st[j]); st[j] = fmaf(crf[1],  v0.y, st[j]);
            st[j] = fmaf(crf[2],  v0.z, st[j]); st[j] = fmaf(crf[3],  v0.w, st[j]);
            st[j] = fmaf(crf[4],  v1.x, st[j]); st[j] = fmaf(crf[5],  v1.y, st[j]);
            st[j] = fmaf(crf[6],  v1.z, st[j]); st[j] = fmaf(crf[7],  v1.w, st[j]);
            st[j] = fmaf(crf[8],  v2.x, st[j]); st[j] = fmaf(crf[9],  v2.y, st[j]);
            st[j] = fmaf(crf[10], v2.z, st[j]); st[j] = fmaf(crf[11], v2.w, st[j]);
            st[j] = fmaf(crf[12], v3.x, st[j]); st[j] = fmaf(crf[13], v3.y, st[j]);
            st[j] = fmaf(crf[14], v3.z, st[j]); st[j] = fmaf(crf[15], v3.w, st[j]);
        }
    }
#pragma unroll
    for (int j = 0; j < 16; ++j)
        st[j] = leaky(uq_l + dts[tb + j] + st[j]);

    int nv = (q == 0) ? 5 : 4;
    float su[4];
#pragma unroll
    for (int j = 0; j < 4; ++j) {
        int u = q + 1 + 4 * j;
        bool ok = (pl + u < Lq) && (maskf[ls + 16 + u] > 0.5f);
        su[j] = ok ? leaky(uqe[ls + 16 + u] + dsv_l + dots_s[ls * 19 + u])
                   : MASK_FILL;
    }

    float m = st[0];
#pragma unroll
    for (int j = 1; j < 16; ++j) m = fmaxf(m, st[j]);
#pragma unroll
    for (int j = 0; j < 5; ++j) {
        if (j < nv) {
            int v = q + 4 * j;
            if ((pl + v >= 16) && (cmask > 0.5f))
                m = fmaxf(m, leaky(uq_l + dsve[ls + v] + dot_self));
        }
    }
#pragma unroll
    for (int j = 0; j < 4; ++j) m = fmaxf(m, su[j]);
    m = fmaxf(m, __shfl_xor(m, 1));
    m = fmaxf(m, __shfl_xor(m, 2));
    float sum = 0.f, wself = 0.f;
#pragma unroll
    for (int j = 0; j < 16; ++j) { st[j] = __expf(st[j] - m); sum += st[j]; }
#pragma unroll
    for (int j = 0; j < 5; ++j) {
        if (j < nv) {
            int v = q + 4 * j;
            if ((pl + v >= 16) && (cmask > 0.5f)) {
                float e = __expf(leaky(uq_l + dsve[ls + v] + dot_self) - m);
                wself += e; sum += e;
            }
        }
    }
#pragma unroll
    for (int j = 0; j < 4; ++j)  { su[j] = __expf(su[j] - m); sum += su[j]; }
    sum += __shfl_xor(sum, 1);
    sum += __shfl_xor(sum, 2);
    float inv = 1.f / sum;
#pragma unroll
    for (int j = 0; j < 16; ++j) st[j] *= inv;
    wself *= inv;
#pragma unroll
    for (int j = 0; j < 4; ++j)  su[j] *= inv;

    float* dstrow = update + (size_t)(b * Lq + pl) * Hq + n * Dq;
#pragma unroll
    for (int c = 0; c < 4; ++c) {
        float u8[8];
#pragma unroll
        for (int e = 0; e < 8; ++e) u8[e] = 0.f;
#pragma unroll 2
        for (int j = 0; j < 16; ++j) {
            const float* vp = &tts2_s[(tb + j) * 36 + 4 * q + 8 * c];
            float4 a0 = ((const float4*)vp)[0];
            float4 a1 = ((const float4*)vp)[1];
            float wt = st[j];
            u8[0] = fmaf(wt, a0.x, u8[0]); u8[1] = fmaf(wt, a0.y, u8[1]);
            u8[2] = fmaf(wt, a0.z, u8[2]); u8[3] = fmaf(wt, a0.w, u8[3]);
            u8[4] = fmaf(wt, a1.x, u8[4]); u8[5] = fmaf(wt, a1.y, u8[5]);
            u8[6] = fmaf(wt, a1.z, u8[6]); u8[7] = fmaf(wt, a1.w, u8[7]);
        }
#pragma unroll
        for (int e = 0; e < 8; ++e)
            u8[e] = fmaf(wself, chx_s[(8 * c + e) * 97 + ls + 16], u8[e]);
#pragma unroll
        for (int j = 0; j < 4; ++j) {
            float wu = su[j];
            int u = q + 1 + 4 * j;
#pragma unroll
            for (int e = 0; e < 8; ++e)
                u8[e] = fmaf(wu, chx_s[(8 * c + e) * 97 + ls + 16 + u], u8[e]);
        }
#pragma unroll
        for (int e = 0; e < 8; ++e) {
            u8[e] += __shfl_xor(u8[e], 1);
            u8[e] += __shfl_xor(u8[e], 2);
        }
        if (q == c) {
            ((float4*)(dstrow + 8 * c))[0] = make_float4(u8[0], u8[1], u8[2], u8[3]);
            ((float4*)(dstrow + 8 * c))[1] = make_float4(u8[4], u8[5], u8[6], u8[7]);
        }
    }
}

// ---------------- output GEMM via MFMA + tanh ----------------
__global__ void __launch_bounds__(256) k_out(
        const float* __restrict__ update, const float* __restrict__ ctx,
        const uint16_t* __restrict__ wp_hi, const uint16_t* __restrict__ wp_lo,
        const float* __restrict__ bo, float* __restrict__ out) {
    int row0 = blockIdx.x * MB;
    int tid = threadIdx.x;
    int w = tid >> 6, l = tid & 63;
    __shared__ __align__(16) char smem_raw[MB * APAD * 4];
    uint16_t* a_hi = (uint16_t*)smem_raw;
    uint16_t* a_lo = a_hi + MB * APAD;

    {
        const float4* s0 = (const float4*)(update + (size_t)row0 * Hq);
        const float4* s1 = (const float4*)(ctx + (size_t)row0 * Hq);
#pragma unroll
        for (int j = 0; j < 4; ++j) {
            int f = tid + j * 256;
            int r = f >> 6, cg = f & 63;
            float4 a = s0[f], bv = s1[f];
            float4 v; v.x = a.x + bv.x; v.y = a.y + bv.y;
            v.z = a.z + bv.z; v.w = a.w + bv.w;
            uint16_t h0 = f2bf(v.x), h1 = f2bf(v.y), h2 = f2bf(v.z), h3 = f2bf(v.w);
            ushort4 hh = {h0, h1, h2, h3};
            ushort4 ll = {f2bf(v.x - bf2f(h0)), f2bf(v.y - bf2f(h1)),
                          f2bf(v.z - bf2f(h2)), f2bf(v.w - bf2f(h3))};
            *(ushort4*)&a_hi[r * APAD + cg * 4] = hh;
            *(ushort4*)&a_lo[r * APAD + cg * 4] = ll;
        }
    }
    __syncthreads();

    int nt0 = w * 4;
    int m = l & 15, quad = l >> 4;
    f32x4 acc[4];
#pragma unroll
    for (int t = 0; t < 4; ++t) acc[t] = (f32x4){0.f, 0.f, 0.f, 0.f};
#pragma unroll
    for (int kc = 0; kc < 8; ++kc) {
        short8 ah = *(const short8*)&a_hi[m * APAD + kc * 32 + quad * 8];
        short8 al = *(const short8*)&a_lo[m * APAD + kc * 32 + quad * 8];
#pragma unroll
        for (int t = 0; t < 4; ++t) {
            int fragi = (nt0 + t) * 8 + kc;
            short8 wh = *(const short8*)&wp_hi[fragi * 512 + l * 8];
            short8 wl = *(const short8*)&wp_lo[fragi * 512 + l * 8];
            acc[t] = __builtin_amdgcn_mfma_f32_16x16x32_bf16(ah, wh, acc[t], 0, 0, 0);
            acc[t] = __builtin_amdgcn_mfma_f32_16x16x32_bf16(ah, wl, acc[t], 0, 0, 0);
            acc[t] = __builtin_amdgcn_mfma_f32_16x16x32_bf16(al, wh, acc[t], 0, 0, 0);
        }
    }
    // epilogue: tanh + direct store (C layout: row=quad*4+r, col=16*(nt0+t)+m)
#pragma unroll
    for (int t = 0; t < 4; ++t) {
        int col = (nt0 + t) * 16 + m;
        float bv = bo[col];
#pragma unroll
        for (int r = 0; r < 4; ++r)
            out[(size_t)(row0 + quad * 4 + r) * Hq + col] = tanhf(acc[t][r] + bv);
    }
}

extern "C" void kernel_launch(void* const* d_in, const int* in_sizes, int n_in,
                              void* d_out, int out_size, void* d_ws, size_t ws_size,
                              hipStream_t stream) {
    const float* context   = (const float*)d_in[0];
    const float* types     = (const float*)d_in[1];
    const unsigned char* cmask = (const unsigned char*)d_in[2];
    const float* W_types   = (const float*)d_in[3];
    const float* b_types   = (const float*)d_in[4];
    const float* W_context = (const float*)d_in[5];
    const float* b_context = (const float*)d_in[6];
    const float* upon      = (const float*)d_in[7];
    const float* down      = (const float*)d_in[8];
    const float* cross     = (const float*)d_in[9];
    const float* W_out     = (const float*)d_in[10];
    const float* b_out     = (const float*)d_in[11];
    float* out = (float*)d_out;
    float* ws  = (float*)d_ws;

    // ws: ctx_hT (16MB) + update (16MB) + W packs (512 KB) = 33.05 MB
    float* ctx_hT   = ws;             // [b][n][d][l]
    float* update   = ws + 4194304;
    uint16_t* wcp_hi = (uint16_t*)(ws + 8388608);
    uint16_t* wcp_lo = wcp_hi + 65536;
    uint16_t* wop_hi = wcp_hi + 131072;
    uint16_t* wop_lo = wcp_hi + 196608;

    // Small intermediates in d_out scratch (k_out overwrites all of d_out last).
    float* types_h  = out;            // 65536   [b][t][h]
    float* types_hT = out + 65536;    // 65536   [b][n][d][t]
    float* down_t   = out + 131072;   // 2048
    float* uqp      = out + 133120;   // 131072
    float* dsvp     = out + 264192;   // 131072

    k_prep<<<128 + Bq * Tq, 256, 0, stream>>>(W_context, W_out,
                                              wcp_hi, wcp_lo, wop_hi, wop_lo,
                                              types, W_types, b_types, down,
                                              types_h, types_hT, down_t);
    k_ctx<<<Bq * Lq / MB, 256, 0, stream>>>(context, wcp_hi, wcp_lo, b_context,
                                            upon, down, ctx_hT, uqp, dsvp);
    k_attn<<<Bq * NHq * (Lq / TLq), 256, 0, stream>>>(ctx_hT, types_h, types_hT, cross,
                                                      uqp, dsvp, down_t, cmask, update);
    k_out<<<Bq * Lq / MB, 256, 0, stream>>>(update, context, wop_hi, wop_lo, b_out, out);
}

// Round 2
// 177.889 us; speedup vs baseline: 1.0681x; 1.0681x over previous
//
#include <hip/hip_runtime.h>
#include <cstdint>

#define Bq 4
#define Lq 4096
#define Hq 256
#define NHq 8
#define Tq 64
#define WINq 16
#define Dq 32
#define NEG_SLOPE 5.0f
#define MASK_FILL -1e12f
#define TLq 64         // l-tile for k_attn
#define MB 16          // rows per block for MFMA GEMMs (1024 blocks -> 4/CU)

typedef __attribute__((ext_vector_type(8))) short short8;
typedef __attribute__((ext_vector_type(4))) float f32x4;

__device__ __forceinline__ float leaky(float x) { return x >= 0.f ? x : NEG_SLOPE * x; }

__device__ __forceinline__ uint16_t f2bf(float x) {   // RNE f32->bf16 bits
    uint32_t u = __float_as_uint(x);
    uint32_t r = (u + 0x7fffu + ((u >> 16) & 1u)) >> 16;
    return (uint16_t)r;
}
__device__ __forceinline__ float bf2f(uint16_t h) {
    return __uint_as_float(((uint32_t)h) << 16);
}

// ------- merged prep: blocks 0..127 pack Wc/Wo; blocks 128..383 do types -------
__global__ void k_prep(const float* __restrict__ Wc, const float* __restrict__ Wo,
                       uint16_t* __restrict__ pc_hi, uint16_t* __restrict__ pc_lo,
                       uint16_t* __restrict__ po_hi, uint16_t* __restrict__ po_lo,
                       const float* __restrict__ types, const float* __restrict__ Wt,
                       const float* __restrict__ bt, const float* __restrict__ down,
                       float* __restrict__ types_h, float* __restrict__ types_hT,
                       float* __restrict__ down_t) {
    __shared__ float sin[Hq];
    __shared__ float outr[Hq];
    if (blockIdx.x < 128) {
        int wsel = blockIdx.x >> 6;
        int blk = blockIdx.x & 63;
        const float* W = wsel ? Wo : Wc;
        uint16_t* ph = wsel ? po_hi : pc_hi;
        uint16_t* pl = wsel ? po_lo : pc_lo;
        int base = blk * 1024;
        for (int idx = base + threadIdx.x; idx < base + 1024; idx += 256) {
            int j = idx & 7, l = (idx >> 3) & 63, fragi = idx >> 9;
            int kc = fragi & 7, nt = fragi >> 3;
            int k = kc * 32 + (l >> 4) * 8 + j;
            int c = nt * 16 + (l & 15);
            float x = W[k * Hq + c];
            uint16_t h = f2bf(x);
            ph[idx] = h;
            pl[idx] = f2bf(x - bf2f(h));
        }
        return;
    }
    // ---- types projection + down_t + transposed copy ----
    int row = blockIdx.x - 128;    // b*T + t
    int h = threadIdx.x;
    int b = row >> 6, t = row & 63;
    sin[h] = types[(size_t)row * Hq + h];
    __syncthreads();
    float acc = bt[h];
    for (int k = 0; k < Hq; k += 4) {
        float4 iv = *(const float4*)&sin[k];
        acc = fmaf(iv.x, Wt[(k + 0) * Hq + h], acc);
        acc = fmaf(iv.y, Wt[(k + 1) * Hq + h], acc);
        acc = fmaf(iv.z, Wt[(k + 2) * Hq + h], acc);
        acc = fmaf(iv.w, Wt[(k + 3) * Hq + h], acc);
    }
    types_h[(size_t)row * Hq + h] = acc;
    types_hT[(size_t)(b * Hq + h) * Tq + t] = acc;   // [b][n][d][t]
    outr[h] = acc;
    __syncthreads();
    if (h < NHq) {
        float s = 0.f;
        for (int d = 0; d < Dq; ++d) s += outr[h * Dq + d] * down[h * Dq + d];
        down_t[(b * NHq + h) * Tq + t] = s;
    }
}

// ---------------- context projection via MFMA (bf16 hi/lo split) ----------------
#define APAD 264       // bf16 row stride for A tiles
#define OPAD 258       // f32 row stride for output staging
__global__ void __launch_bounds__(256) k_ctx(
        const float* __restrict__ ctx,
        const uint16_t* __restrict__ wp_hi, const uint16_t* __restrict__ wp_lo,
        const float* __restrict__ bc, const float* __restrict__ upon,
        const float* __restrict__ down,
        float* __restrict__ ctx_hT, float* __restrict__ uq,
        float* __restrict__ dsv) {
    int row0 = blockIdx.x * MB;
    int b = row0 >> 12, l0 = row0 & (Lq - 1);
    int tid = threadIdx.x;
    int w = tid >> 6, l = tid & 63;
    __shared__ __align__(16) char smem_raw[MB * APAD * 4];   // 16.9 KB
    uint16_t* a_hi = (uint16_t*)smem_raw;            // [16][APAD]
    uint16_t* a_lo = a_hi + MB * APAD;
    float* outb = (float*)smem_raw;                  // reused: [16][OPAD]

    {
        const float4* src = (const float4*)(ctx + (size_t)row0 * Hq);
#pragma unroll
        for (int j = 0; j < 4; ++j) {
            int f = tid + j * 256;
            int r = f >> 6, cg = f & 63;
            float4 v = src[f];
            uint16_t h0 = f2bf(v.x), h1 = f2bf(v.y), h2 = f2bf(v.z), h3 = f2bf(v.w);
            ushort4 hh = {h0, h1, h2, h3};
            ushort4 ll = {f2bf(v.x - bf2f(h0)), f2bf(v.y - bf2f(h1)),
                          f2bf(v.z - bf2f(h2)), f2bf(v.w - bf2f(h3))};
            *(ushort4*)&a_hi[r * APAD + cg * 4] = hh;
            *(ushort4*)&a_lo[r * APAD + cg * 4] = ll;
        }
    }
    __syncthreads();

    int nt0 = w * 4;
    int m = l & 15, quad = l >> 4;
    f32x4 acc[4];
#pragma unroll
    for (int t = 0; t < 4; ++t) acc[t] = (f32x4){0.f, 0.f, 0.f, 0.f};
#pragma unroll
    for (int kc = 0; kc < 8; ++kc) {
        short8 ah = *(const short8*)&a_hi[m * APAD + kc * 32 + quad * 8];
        short8 al = *(const short8*)&a_lo[m * APAD + kc * 32 + quad * 8];
#pragma unroll
        for (int t = 0; t < 4; ++t) {
            int fragi = (nt0 + t) * 8 + kc;
            short8 wh = *(const short8*)&wp_hi[fragi * 512 + l * 8];
            short8 wl = *(const short8*)&wp_lo[fragi * 512 + l * 8];
            acc[t] = __builtin_amdgcn_mfma_f32_16x16x32_bf16(ah, wh, acc[t], 0, 0, 0);
            acc[t] = __builtin_amdgcn_mfma_f32_16x16x32_bf16(ah, wl, acc[t], 0, 0, 0);
            acc[t] = __builtin_amdgcn_mfma_f32_16x16x32_bf16(al, wh, acc[t], 0, 0, 0);
        }
    }
    __syncthreads();

#pragma unroll
    for (int t = 0; t < 4; ++t) {
        int col = (nt0 + t) * 16 + m;
        float bv = bc[col];
#pragma unroll
        for (int r = 0; r < 4; ++r)
            outb[(quad * 4 + r) * OPAD + col] = acc[t][r] + bv;
    }
    __syncthreads();

    if (tid < MB * NHq) {
        int r = tid >> 3, n = tid & 7;
        float su = 0.f, sd = 0.f;
        for (int d = 0; d < Dq; ++d) {
            float v = outb[r * OPAD + n * Dq + d];
            su += v * upon[n * Dq + d];
            sd += v * down[n * Dq + d];
        }
        uq[(b * NHq + n) * Lq + l0 + r] = su;
        dsv[(b * NHq + n) * Lq + l0 + r] = sd;
    }
    {
        float* dst = ctx_hT + (size_t)(b * Hq + tid) * Lq + l0;
#pragma unroll
        for (int j = 0; j < MB / 4; ++j) {
            float4 o;
            o.x = outb[(4 * j + 0) * OPAD + tid];
            o.y = outb[(4 * j + 1) * OPAD + tid];
            o.z = outb[(4 * j + 2) * OPAD + tid];
            o.w = outb[(4 * j + 3) * OPAD + tid];
            ((float4*)dst)[j] = o;
        }
    }
}

// ---------------- attention: tiled (b, n, 64 l's) per block ----------------
// R11: scores unchanged (verified); epilogue (upd_t + upd_c) moved to MFMA:
//   updT[d][l] = sum_slot V^T[d][slot] * w[l][slot], bf16 hi/lo split.
// LDS phases aliased; dots_s removed (register keep). 36928 B -> 4 blocks/CU.
#define WAT_STRIDE 72    // bf16 units, k-extent 64 (t-slots)
#define TTVT_STRIDE 72   // bf16 units, k-extent 64
#define CHVT_STRIDE 104  // bf16 units, k-extent 96 (window pos)
#define WAW_STRIDE 48    // bf16 units, band-local window slots
__global__ void __launch_bounds__(256, 4) k_attn(
        const float* __restrict__ ctx_hT, const float* __restrict__ types_h,
        const float* __restrict__ types_hT, const float* __restrict__ cross,
        const float* __restrict__ uq, const float* __restrict__ dsv,
        const float* __restrict__ dt, const unsigned char* __restrict__ maskp,
        float* __restrict__ update) {
    int blk = blockIdx.x;
    int lt = blk & 63, n = (blk >> 6) & 7, b = blk >> 9;
    int l0 = lt * TLq;
    int tid = threadIdx.x;
    int ls = tid >> 2;
    int q  = tid & 3;
    int pl = l0 + ls;
    bool mask_b8 = (maskp[1] != 0);

    __shared__ __align__(16) char smem[36928];
    // score-phase region [0, 26304):
    float* chx_s  = (float*)(smem);            // [32][97] f32  (12416 B)
    float* crs_s  = (float*)(smem + 12416);    // [32][36] f32  (4608 B)
    float* tts2_s = (float*)(smem + 17024);    // 64*36+16 f32  (9280 B)
    // aliases over the same region (used strictly after score reads finish):
    uint16_t* waT_hi  = (uint16_t*)(smem);           // [64][72]  (9216 B)
    uint16_t* waT_lo  = (uint16_t*)(smem + 9216);    //           (9216 B)
    uint16_t* chvt_hi = (uint16_t*)(smem);           // [32][104] (6656 B)
    uint16_t* chvt_lo = (uint16_t*)(smem + 6656);    //           (6656 B)
    uint16_t* waw_hi  = (uint16_t*)(smem + 13312);   // [64][48]  (6144 B)
    uint16_t* waw_lo  = (uint16_t*)(smem + 19456);   //           (6144 B)
    // persistent:
    uint16_t* ttvt_hi = (uint16_t*)(smem + 26304);   // [32][72]  (4608 B)
    uint16_t* ttvt_lo = (uint16_t*)(smem + 30912);   //           (4608 B)
    float* uqe   = (float*)(smem + 35520);   // 96
    float* dsve  = (float*)(smem + 35904);   // 96
    float* maskf = (float*)(smem + 36288);   // 96
    float* dts   = (float*)(smem + 36672);   // 64   (end 36928)

    // ---------------- phase 0: staging ----------------
    float chvv[12];    // this thread's 12 window values, kept for chvt write
    {
        int d = tid >> 3, k = tid & 7;
        const float* grow = ctx_hT + ((size_t)(b * NHq + n) * Dq + d) * Lq;
        float* lrow = &chx_s[d * 97 + k * 12];
        if (l0 >= 16 && l0 <= Lq - 80) {
            const float4* g = (const float4*)(grow + (l0 - 16) + k * 12);
            float4 v0 = g[0], v1 = g[1], v2 = g[2];
            chvv[0] = v0.x; chvv[1] = v0.y; chvv[2]  = v0.z; chvv[3]  = v0.w;
            chvv[4] = v1.x; chvv[5] = v1.y; chvv[6]  = v1.z; chvv[7]  = v1.w;
            chvv[8] = v2.x; chvv[9] = v2.y; chvv[10] = v2.z; chvv[11] = v2.w;
        } else {
#pragma unroll
            for (int m = 0; m < 12; ++m) {
                int gl = l0 - 16 + k * 12 + m;
                int glw = (gl < 0) ? gl + Lq : ((gl >= Lq) ? gl - Lq : gl);
                chvv[m] = grow[glw];
            }
        }
#pragma unroll
        for (int m = 0; m < 12; ++m) lrow[m] = chvv[m];
    }
    {
        float4 v = ((const float4*)(cross + n * (Dq * Dq)))[tid];
        float* p = &crs_s[(tid >> 3) * 36 + (tid & 7) * 4];
        p[0] = v.x; p[1] = v.y; p[2] = v.z; p[3] = v.w;
    }
    {
        int t = tid >> 2, c4 = tid & 3;
        const float4* src = (const float4*)(types_h + (size_t)(b * Tq + t) * Hq
                                            + n * Dq + 8 * c4);
        float* p = &tts2_s[t * 36 + 4 * (t >> 4) + 8 * c4];
        ((float4*)p)[0] = src[0];
        ((float4*)p)[1] = src[1];
    }
    {   // ttvt: types_h^T [d][t] bf16 hi/lo (B/A fragment layout for upd t-part)
        int d = tid >> 3, tc8 = (tid & 7) * 8;
        const float* src = types_hT + ((size_t)(b * Hq) + n * Dq + d) * Tq + tc8;
        float4 v0 = *(const float4*)src;
        float4 v1 = *(const float4*)(src + 4);
        float vv[8] = {v0.x, v0.y, v0.z, v0.w, v1.x, v1.y, v1.z, v1.w};
        uint hp[4], lp[4];
#pragma unroll
        for (int jj = 0; jj < 4; ++jj) {
            uint16_t h0 = f2bf(vv[2*jj]), h1 = f2bf(vv[2*jj+1]);
            uint16_t e0 = f2bf(vv[2*jj] - bf2f(h0)), e1 = f2bf(vv[2*jj+1] - bf2f(h1));
            hp[jj] = (uint)h0 | ((uint)h1 << 16);
            lp[jj] = (uint)e0 | ((uint)e1 << 16);
        }
        *(uint4*)&ttvt_hi[d * TTVT_STRIDE + tc8] = make_uint4(hp[0], hp[1], hp[2], hp[3]);
        *(uint4*)&ttvt_lo[d * TTVT_STRIDE + tc8] = make_uint4(lp[0], lp[1], lp[2], lp[3]);
    }
    if (tid < 96) {
        int gl = l0 - 16 + tid;
        int glw = (gl < 0) ? gl + Lq : ((gl >= Lq) ? gl - Lq : gl);
        uqe[tid] = uq[(b * NHq + n) * Lq + glw];
        unsigned char mb = mask_b8 ? maskp[b * Lq + glw]
                                   : maskp[(size_t)(b * Lq + glw) * 4];
        maskf[tid] = mb ? 1.f : 0.f;
    } else if (tid < 192) {
        int j = tid - 96;
        int gl = l0 - 16 + j;
        int glw = (gl < 0) ? gl + Lq : ((gl >= Lq) ? gl - Lq : gl);
        dsve[j] = dsv[(b * NHq + n) * Lq + glw];
    } else {
        dts[tid - 192] = dt[(b * NHq + n) * Tq + (tid - 192)];
    }
    __syncthreads();

    // ---------------- scores (unchanged, verified) ----------------
    float a[8];
#pragma unroll
    for (int ii = 0; ii < 8; ++ii) a[ii] = 0.f;
#pragma unroll 2
    for (int d = 0; d < Dq; ++d) {
        float chv = chx_s[d * 97 + ls + 16];
        const float4* cp = (const float4*)(&crs_s[d * 36 + 8 * q]);
        float4 c0 = cp[0], c1 = cp[1];
        a[0] = fmaf(chv, c0.x, a[0]); a[1] = fmaf(chv, c0.y, a[1]);
        a[2] = fmaf(chv, c0.z, a[2]); a[3] = fmaf(chv, c0.w, a[3]);
        a[4] = fmaf(chv, c1.x, a[4]); a[5] = fmaf(chv, c1.y, a[5]);
        a[6] = fmaf(chv, c1.z, a[6]); a[7] = fmaf(chv, c1.w, a[7]);
    }

    float dot_self, sud[4];
    {
#pragma unroll
        for (int u = 0; u < 17; ++u) {
            float acc = 0.f;
#pragma unroll
            for (int k = 0; k < 8; ++k)
                acc = fmaf(a[k], chx_s[(8 * q + k) * 97 + ls + 16 + u], acc);
            acc += __shfl_xor(acc, 1);
            acc += __shfl_xor(acc, 2);
            if (u == 0) dot_self = acc;
            else if (((u - 1) & 3) == q) sud[(u - 1) >> 2] = acc;
        }
    }

    float uq_l = uqe[ls + 16];
    float dsv_l = dsve[ls + 16];
    float cmask = maskf[ls + 16];

    int tb = 16 * q;
    float st[16];
#pragma unroll
    for (int j = 0; j < 16; ++j) st[j] = 0.f;
#pragma unroll
    for (int half = 0; half < 2; ++half) {
        float crf[16];
#pragma unroll
        for (int k = 0; k < 16; ++k)
            crf[k] = __shfl(a[k & 7], 2 * half + (k >> 3), 4);
#pragma unroll 4
        for (int j = 0; j < 16; ++j) {
            const float4* rp =
                (const float4*)&tts2_s[(tb + j) * 36 + 4 * q + 16 * half];
            float4 v0 = rp[0], v1 = rp[1], v2 = rp[2], v3 = rp[3];
            st[j] = fmaf(crf[0],  v0.x, st[j]); st[j] = fmaf(crf[1],  v0.y, st[j]);
            st[j] = fmaf(crf[2],  v0.z, st[j]); st[j] = fmaf(crf[3],  v0.w, st[j]);
            st[j] = fmaf(crf[4],  v1.x, st[j]); st[j] = fmaf(crf[5],  v1.y, st[j]);
            st[j] = fmaf(crf[6],  v1.z, st[j]); st[j] = fmaf(crf[7],  v1.w, st[j]);
            st[j] = fmaf(crf[8],  v2.x, st[j]); st[j] = fmaf(crf[9],  v2.y, st[j]);
            st[j] = fmaf(crf[10], v2.z, st[j]); st[j] = fmaf(crf[11], v2.w, st[j]);
            st[j] = fmaf(crf[12], v3.x, st[j]); st[j] = fmaf(crf[13], v3.y, st[j]);
            st[j] = fmaf(crf[14], v3.z, st[j]); st[j] = fmaf(crf[15], v3.w, st[j]);
        }
    }
#pragma unroll
    for (int j = 0; j < 16; ++j)
        st[j] = leaky(uq_l + dts[tb + j] + st[j]);

    int nv = (q == 0) ? 5 : 4;
    float su[4];
#pragma unroll
    for (int j = 0; j < 4; ++j) {
        int u = q + 1 + 4 * j;
        bool ok = (pl + u < Lq) && (maskf[ls + 16 + u] > 0.5f);
        su[j] = ok ? leaky(uqe[ls + 16 + u] + dsv_l + sud[j])
                   : MASK_FILL;
    }

    float m = st[0];
#pragma unroll
    for (int j = 1; j < 16; ++j) m = fmaxf(m, st[j]);
#pragma unroll
    for (int j = 0; j < 5; ++j) {
        if (j < nv) {
            int v = q + 4 * j;
            if ((pl + v >= 16) && (cmask > 0.5f))
                m = fmaxf(m, leaky(uq_l + dsve[ls + v] + dot_self));
        }
    }
#pragma unroll
    for (int j = 0; j < 4; ++j) m = fmaxf(m, su[j]);
    m = fmaxf(m, __shfl_xor(m, 1));
    m = fmaxf(m, __shfl_xor(m, 2));
    float sum = 0.f, wself = 0.f;
#pragma unroll
    for (int j = 0; j < 16; ++j) { st[j] = __expf(st[j] - m); sum += st[j]; }
#pragma unroll
    for (int j = 0; j < 5; ++j) {
        if (j < nv) {
            int v = q + 4 * j;
            if ((pl + v >= 16) && (cmask > 0.5f)) {
                float e = __expf(leaky(uq_l + dsve[ls + v] + dot_self) - m);
                wself += e; sum += e;
            }
        }
    }
#pragma unroll
    for (int j = 0; j < 4; ++j)  { su[j] = __expf(su[j] - m); sum += su[j]; }
    sum += __shfl_xor(sum, 1);
    sum += __shfl_xor(sum, 2);
    float inv = 1.f / sum;
#pragma unroll
    for (int j = 0; j < 16; ++j) st[j] *= inv;
    wself *= inv;
#pragma unroll
    for (int j = 0; j < 4; ++j)  su[j] *= inv;
    // full self/down weight for value ctx_h[pl]: sum over quad partials
    wself += __shfl_xor(wself, 1);
    wself += __shfl_xor(wself, 2);

    __syncthreads();   // all score-region LDS reads complete; begin aliasing

    // ---------------- phase 4a: write t-part weights (bf16 hi/lo) ----------------
    {
        uint hp[8], lp[8];
#pragma unroll
        for (int jj = 0; jj < 8; ++jj) {
            uint16_t h0 = f2bf(st[2*jj]), h1 = f2bf(st[2*jj+1]);
            uint16_t e0 = f2bf(st[2*jj] - bf2f(h0)), e1 = f2bf(st[2*jj+1] - bf2f(h1));
            hp[jj] = (uint)h0 | ((uint)h1 << 16);
            lp[jj] = (uint)e0 | ((uint)e1 << 16);
        }
        uint16_t* hb = &waT_hi[ls * WAT_STRIDE + tb];
        uint16_t* lb = &waT_lo[ls * WAT_STRIDE + tb];
        *(uint4*)hb       = make_uint4(hp[0], hp[1], hp[2], hp[3]);
        *(uint4*)(hb + 8) = make_uint4(hp[4], hp[5], hp[6], hp[7]);
        *(uint4*)lb       = make_uint4(lp[0], lp[1], lp[2], lp[3]);
        *(uint4*)(lb + 8) = make_uint4(lp[4], lp[5], lp[6], lp[7]);
    }
    __syncthreads();

    // ---------------- phase 5: t-part MFMAs ----------------
    int wv = tid >> 6;            // wave id -> owns l-cols 16*wv..16*wv+15
    int lane = tid & 63;
    int mrow = lane & 15, chunk = lane >> 4;
    f32x4 acc0 = (f32x4){0.f, 0.f, 0.f, 0.f};
    f32x4 acc1 = (f32x4){0.f, 0.f, 0.f, 0.f};
#pragma unroll
    for (int ks = 0; ks < 2; ++ks) {
        short8 bh = *(const short8*)&waT_hi[(16*wv + mrow) * WAT_STRIDE + 32*ks + 8*chunk];
        short8 bl = *(const short8*)&waT_lo[(16*wv + mrow) * WAT_STRIDE + 32*ks + 8*chunk];
        short8 a0h = *(const short8*)&ttvt_hi[mrow * TTVT_STRIDE + 32*ks + 8*chunk];
        short8 a0l = *(const short8*)&ttvt_lo[mrow * TTVT_STRIDE + 32*ks + 8*chunk];
        short8 a1h = *(const short8*)&ttvt_hi[(16 + mrow) * TTVT_STRIDE + 32*ks + 8*chunk];
        short8 a1l = *(const short8*)&ttvt_lo[(16 + mrow) * TTVT_STRIDE + 32*ks + 8*chunk];
        acc0 = __builtin_amdgcn_mfma_f32_16x16x32_bf16(a0h, bh, acc0, 0, 0, 0);
        acc0 = __builtin_amdgcn_mfma_f32_16x16x32_bf16(a0l, bh, acc0, 0, 0, 0);
        acc0 = __builtin_amdgcn_mfma_f32_16x16x32_bf16(a0h, bl, acc0, 0, 0, 0);
        acc1 = __builtin_amdgcn_mfma_f32_16x16x32_bf16(a1h, bh, acc1, 0, 0, 0);
        acc1 = __builtin_amdgcn_mfma_f32_16x16x32_bf16(a1l, bh, acc1, 0, 0, 0);
        acc1 = __builtin_amdgcn_mfma_f32_16x16x32_bf16(a1h, bl, acc1, 0, 0, 0);
    }
    __syncthreads();   // waT reads done; region reused for chvt

    // ---------------- phase 5.5: write chvt (values) + zero window weights ----
    {
        int d = tid >> 3, k = tid & 7;
        uint hp[6], lp[6];
#pragma unroll
        for (int jj = 0; jj < 6; ++jj) {
            uint16_t h0 = f2bf(chvv[2*jj]), h1 = f2bf(chvv[2*jj+1]);
            uint16_t e0 = f2bf(chvv[2*jj] - bf2f(h0)), e1 = f2bf(chvv[2*jj+1] - bf2f(h1));
            hp[jj] = (uint)h0 | ((uint)h1 << 16);
            lp[jj] = (uint)e0 | ((uint)e1 << 16);
        }
        uint16_t* hb = &chvt_hi[d * CHVT_STRIDE + k * 12];
        uint16_t* lb = &chvt_lo[d * CHVT_STRIDE + k * 12];
        *(uint2*)(hb)     = make_uint2(hp[0], hp[1]);
        *(uint2*)(hb + 4) = make_uint2(hp[2], hp[3]);
        *(uint2*)(hb + 8) = make_uint2(hp[4], hp[5]);
        *(uint2*)(lb)     = make_uint2(lp[0], lp[1]);
        *(uint2*)(lb + 4) = make_uint2(lp[2], lp[3]);
        *(uint2*)(lb + 8) = make_uint2(lp[4], lp[5]);
    }
    {
        float4 z = make_float4(0.f, 0.f, 0.f, 0.f);
        float4* wz = (float4*)waw_hi;   // waw_hi + waw_lo contiguous: 12288 B
        for (int i = tid; i < 768; i += 256) wz[i] = z;
    }
    __syncthreads();

    // ---------------- phase 5.75: scatter window weights ----------------
    {
        int jself = (ls & 15) + 16;   // band-local self slot for row ls
#pragma unroll
        for (int j = 0; j < 4; ++j) {
            int col = jself + q + 1 + 4 * j;
            float v = su[j];
            uint16_t h = f2bf(v);
            waw_hi[ls * WAW_STRIDE + col] = h;
            waw_lo[ls * WAW_STRIDE + col] = f2bf(v - bf2f(h));
        }
        if (q == 0) {
            uint16_t h = f2bf(wself);
            waw_hi[ls * WAW_STRIDE + jself] = h;
            waw_lo[ls * WAW_STRIDE + jself] = f2bf(wself - bf2f(h));
        }
    }
    __syncthreads();

    // ---------------- phase 6: window-part MFMAs (single K-step per tile) ----
    {
        short8 bh = *(const short8*)&waw_hi[(16*wv + mrow) * WAW_STRIDE + 16 + 8*chunk];
        short8 bl = *(const short8*)&waw_lo[(16*wv + mrow) * WAW_STRIDE + 16 + 8*chunk];
        int kabs = 16*wv + 16 + 8*chunk;
        short8 a0h = *(const short8*)&chvt_hi[mrow * CHVT_STRIDE + kabs];
        short8 a0l = *(const short8*)&chvt_lo[mrow * CHVT_STRIDE + kabs];
        short8 a1h = *(const short8*)&chvt_hi[(16 + mrow) * CHVT_STRIDE + kabs];
        short8 a1l = *(const short8*)&chvt_lo[(16 + mrow) * CHVT_STRIDE + kabs];
        acc0 = __builtin_amdgcn_mfma_f32_16x16x32_bf16(a0h, bh, acc0, 0, 0, 0);
        acc0 = __builtin_amdgcn_mfma_f32_16x16x32_bf16(a0l, bh, acc0, 0, 0, 0);
        acc0 = __builtin_amdgcn_mfma_f32_16x16x32_bf16(a0h, bl, acc0, 0, 0, 0);
        acc1 = __builtin_amdgcn_mfma_f32_16x16x32_bf16(a1h, bh, acc1, 0, 0, 0);
        acc1 = __builtin_amdgcn_mfma_f32_16x16x32_bf16(a1l, bh, acc1, 0, 0, 0);
        acc1 = __builtin_amdgcn_mfma_f32_16x16x32_bf16(a1h, bl, acc1, 0, 0, 0);
    }

    // ---------------- C write: updT[d][l] -> update[b][l][n*32+d] ----------------
    {
        int lcol = l0 + 16 * wv + mrow;     // C col = n-dim = l
        float* dst = update + (size_t)(b * Lq + lcol) * Hq + n * Dq + 4 * chunk;
        *(float4*)dst        = make_float4(acc0[0], acc0[1], acc0[2], acc0[3]);
        *(float4*)(dst + 16) = make_float4(acc1[0], acc1[1], acc1[2], acc1[3]);
    }
}

// ---------------- output GEMM via MFMA + tanh ----------------
__global__ void __launch_bounds__(256) k_out(
        const float* __restrict__ update, const float* __restrict__ ctx,
        const uint16_t* __restrict__ wp_hi, const uint16_t* __restrict__ wp_lo,
        const float* __restrict__ bo, float* __restrict__ out) {
    int row0 = blockIdx.x * MB;
    int tid = threadIdx.x;
    int w = tid >> 6, l = tid & 63;
    __shared__ __align__(16) char smem_raw[MB * APAD * 4];
    uint16_t* a_hi = (uint16_t*)smem_raw;
    uint16_t* a_lo = a_hi + MB * APAD;

    {
        const float4* s0 = (const float4*)(update + (size_t)row0 * Hq);
        const float4* s1 = (const float4*)(ctx + (size_t)row0 * Hq);
#pragma unroll
        for (int j = 0; j < 4; ++j) {
            int f = tid + j * 256;
            int r = f >> 6, cg = f & 63;
            float4 a = s0[f], bv = s1[f];
            float4 v; v.x = a.x + bv.x; v.y = a.y + bv.y;
            v.z = a.z + bv.z; v.w = a.w + bv.w;
            uint16_t h0 = f2bf(v.x), h1 = f2bf(v.y), h2 = f2bf(v.z), h3 = f2bf(v.w);
            ushort4 hh = {h0, h1, h2, h3};
            ushort4 ll = {f2bf(v.x - bf2f(h0)), f2bf(v.y - bf2f(h1)),
                          f2bf(v.z - bf2f(h2)), f2bf(v.w - bf2f(h3))};
            *(ushort4*)&a_hi[r * APAD + cg * 4] = hh;
            *(ushort4*)&a_lo[r * APAD + cg * 4] = ll;
        }
    }
    __syncthreads();

    int nt0 = w * 4;
    int m = l & 15, quad = l >> 4;
    f32x4 acc[4];
#pragma unroll
    for (int t = 0; t < 4; ++t) acc[t] = (f32x4){0.f, 0.f, 0.f, 0.f};
#pragma unroll
    for (int kc = 0; kc < 8; ++kc) {
        short8 ah = *(const short8*)&a_hi[m * APAD + kc * 32 + quad * 8];
        short8 al = *(const short8*)&a_lo[m * APAD + kc * 32 + quad * 8];
#pragma unroll
        for (int t = 0; t < 4; ++t) {
            int fragi = (nt0 + t) * 8 + kc;
            short8 wh = *(const short8*)&wp_hi[fragi * 512 + l * 8];
            short8 wl = *(const short8*)&wp_lo[fragi * 512 + l * 8];
            acc[t] = __builtin_amdgcn_mfma_f32_16x16x32_bf16(ah, wh, acc[t], 0, 0, 0);
            acc[t] = __builtin_amdgcn_mfma_f32_16x16x32_bf16(ah, wl, acc[t], 0, 0, 0);
            acc[t] = __builtin_amdgcn_mfma_f32_16x16x32_bf16(al, wh, acc[t], 0, 0, 0);
        }
    }
#pragma unroll
    for (int t = 0; t < 4; ++t) {
        int col = (nt0 + t) * 16 + m;
        float bv = bo[col];
#pragma unroll
        for (int r = 0; r < 4; ++r)
            out[(size_t)(row0 + quad * 4 + r) * Hq + col] = tanhf(acc[t][r] + bv);
    }
}

extern "C" void kernel_launch(void* const* d_in, const int* in_sizes, int n_in,
                              void* d_out, int out_size, void* d_ws, size_t ws_size,
                              hipStream_t stream) {
    const float* context   = (const float*)d_in[0];
    const float* types     = (const float*)d_in[1];
    const unsigned char* cmask = (const unsigned char*)d_in[2];
    const float* W_types   = (const float*)d_in[3];
    const float* b_types   = (const float*)d_in[4];
    const float* W_context = (const float*)d_in[5];
    const float* b_context = (const float*)d_in[6];
    const float* upon      = (const float*)d_in[7];
    const float* down      = (const float*)d_in[8];
    const float* cross     = (const float*)d_in[9];
    const float* W_out     = (const float*)d_in[10];
    const float* b_out     = (const float*)d_in[11];
    float* out = (float*)d_out;
    float* ws  = (float*)d_ws;

    float* ctx_hT   = ws;             // [b][n][d][l]
    float* update   = ws + 4194304;
    uint16_t* wcp_hi = (uint16_t*)(ws + 8388608);
    uint16_t* wcp_lo = wcp_hi + 65536;
    uint16_t* wop_hi = wcp_hi + 131072;
    uint16_t* wop_lo = wcp_hi + 196608;

    float* types_h  = out;            // 65536   [b][t][h]
    float* types_hT = out + 65536;    // 65536   [b][n][d][t]
    float* down_t   = out + 131072;   // 2048
    float* uqp      = out + 133120;   // 131072
    float* dsvp     = out + 264192;   // 131072

    k_prep<<<128 + Bq * Tq, 256, 0, stream>>>(W_context, W_out,
                                              wcp_hi, wcp_lo, wop_hi, wop_lo,
                                              types, W_types, b_types, down,
                                              types_h, types_hT, down_t);
    k_ctx<<<Bq * Lq / MB, 256, 0, stream>>>(context, wcp_hi, wcp_lo, b_context,
                                            upon, down, ctx_hT, uqp, dsvp);
    k_attn<<<Bq * NHq * (Lq / TLq), 256, 0, stream>>>(ctx_hT, types_h, types_hT, cross,
                                                      uqp, dsvp, down_t, cmask, update);
    k_out<<<Bq * Lq / MB, 256, 0, stream>>>(update, context, wop_hi, wop_lo, b_out, out);
}

// Round 3
// 165.964 us; speedup vs baseline: 1.1449x; 1.0719x over previous
//
#include <hip/hip_runtime.h>
#include <cstdint>

#define Bq 4
#define Lq 4096
#define Hq 256
#define NHq 8
#define Tq 64
#define WINq 16
#define Dq 32
#define NEG_SLOPE 5.0f
#define MASK_FILL -1e12f
#define TLq 64         // l-tile for k_attn
#define MB 16          // rows per block for MFMA GEMMs (1024 blocks -> 4/CU)

typedef __attribute__((ext_vector_type(8))) short short8;
typedef __attribute__((ext_vector_type(4))) float f32x4;

__device__ __forceinline__ float leaky(float x) { return x >= 0.f ? x : NEG_SLOPE * x; }

__device__ __forceinline__ uint16_t f2bf(float x) {   // RNE f32->bf16 bits
    uint32_t u = __float_as_uint(x);
    uint32_t r = (u + 0x7fffu + ((u >> 16) & 1u)) >> 16;
    return (uint16_t)r;
}
__device__ __forceinline__ float bf2f(uint16_t h) {
    return __uint_as_float(((uint32_t)h) << 16);
}

// ------- merged prep: blocks 0..127 pack Wc/Wo; blocks 128..383 do types -------
__global__ void k_prep(const float* __restrict__ Wc, const float* __restrict__ Wo,
                       uint16_t* __restrict__ pc_hi, uint16_t* __restrict__ pc_lo,
                       uint16_t* __restrict__ po_hi, uint16_t* __restrict__ po_lo,
                       const float* __restrict__ types, const float* __restrict__ Wt,
                       const float* __restrict__ bt, const float* __restrict__ down,
                       float* __restrict__ types_h, float* __restrict__ types_hT,
                       float* __restrict__ down_t) {
    __shared__ float sin[Hq];
    __shared__ float outr[Hq];
    if (blockIdx.x < 128) {
        int wsel = blockIdx.x >> 6;
        int blk = blockIdx.x & 63;
        const float* W = wsel ? Wo : Wc;
        uint16_t* ph = wsel ? po_hi : pc_hi;
        uint16_t* pl = wsel ? po_lo : pc_lo;
        int base = blk * 1024;
        for (int idx = base + threadIdx.x; idx < base + 1024; idx += 256) {
            int j = idx & 7, l = (idx >> 3) & 63, fragi = idx >> 9;
            int kc = fragi & 7, nt = fragi >> 3;
            int k = kc * 32 + (l >> 4) * 8 + j;
            int c = nt * 16 + (l & 15);
            float x = W[k * Hq + c];
            uint16_t h = f2bf(x);
            ph[idx] = h;
            pl[idx] = f2bf(x - bf2f(h));
        }
        return;
    }
    // ---- types projection + down_t + transposed copy ----
    int row = blockIdx.x - 128;    // b*T + t
    int h = threadIdx.x;
    int b = row >> 6, t = row & 63;
    sin[h] = types[(size_t)row * Hq + h];
    __syncthreads();
    float acc = bt[h];
    for (int k = 0; k < Hq; k += 4) {
        float4 iv = *(const float4*)&sin[k];
        acc = fmaf(iv.x, Wt[(k + 0) * Hq + h], acc);
        acc = fmaf(iv.y, Wt[(k + 1) * Hq + h], acc);
        acc = fmaf(iv.z, Wt[(k + 2) * Hq + h], acc);
        acc = fmaf(iv.w, Wt[(k + 3) * Hq + h], acc);
    }
    types_h[(size_t)row * Hq + h] = acc;
    types_hT[(size_t)(b * Hq + h) * Tq + t] = acc;   // [b][n][d][t]
    outr[h] = acc;
    __syncthreads();
    if (h < NHq) {
        float s = 0.f;
        for (int d = 0; d < Dq; ++d) s += outr[h * Dq + d] * down[h * Dq + d];
        down_t[(b * NHq + h) * Tq + t] = s;
    }
}

// ---------------- context projection via MFMA (bf16 hi/lo split) ----------------
#define APAD 264       // bf16 row stride for A tiles
#define OPAD 258       // f32 row stride for output staging
__global__ void __launch_bounds__(256) k_ctx(
        const float* __restrict__ ctx,
        const uint16_t* __restrict__ wp_hi, const uint16_t* __restrict__ wp_lo,
        const float* __restrict__ bc, const float* __restrict__ upon,
        const float* __restrict__ down,
        float* __restrict__ ctx_hT, float* __restrict__ uq,
        float* __restrict__ dsv) {
    int row0 = blockIdx.x * MB;
    int b = row0 >> 12, l0 = row0 & (Lq - 1);
    int tid = threadIdx.x;
    int w = tid >> 6, l = tid & 63;
    __shared__ __align__(16) char smem_raw[MB * APAD * 4];   // 16.9 KB
    uint16_t* a_hi = (uint16_t*)smem_raw;            // [16][APAD]
    uint16_t* a_lo = a_hi + MB * APAD;
    float* outb = (float*)smem_raw;                  // reused: [16][OPAD]

    {
        const float4* src = (const float4*)(ctx + (size_t)row0 * Hq);
#pragma unroll
        for (int j = 0; j < 4; ++j) {
            int f = tid + j * 256;
            int r = f >> 6, cg = f & 63;
            float4 v = src[f];
            uint16_t h0 = f2bf(v.x), h1 = f2bf(v.y), h2 = f2bf(v.z), h3 = f2bf(v.w);
            ushort4 hh = {h0, h1, h2, h3};
            ushort4 ll = {f2bf(v.x - bf2f(h0)), f2bf(v.y - bf2f(h1)),
                          f2bf(v.z - bf2f(h2)), f2bf(v.w - bf2f(h3))};
            *(ushort4*)&a_hi[r * APAD + cg * 4] = hh;
            *(ushort4*)&a_lo[r * APAD + cg * 4] = ll;
        }
    }
    __syncthreads();

    int nt0 = w * 4;
    int m = l & 15, quad = l >> 4;
    f32x4 acc[4];
#pragma unroll
    for (int t = 0; t < 4; ++t) acc[t] = (f32x4){0.f, 0.f, 0.f, 0.f};
#pragma unroll
    for (int kc = 0; kc < 8; ++kc) {
        short8 ah = *(const short8*)&a_hi[m * APAD + kc * 32 + quad * 8];
        short8 al = *(const short8*)&a_lo[m * APAD + kc * 32 + quad * 8];
#pragma unroll
        for (int t = 0; t < 4; ++t) {
            int fragi = (nt0 + t) * 8 + kc;
            short8 wh = *(const short8*)&wp_hi[fragi * 512 + l * 8];
            short8 wl = *(const short8*)&wp_lo[fragi * 512 + l * 8];
            acc[t] = __builtin_amdgcn_mfma_f32_16x16x32_bf16(ah, wh, acc[t], 0, 0, 0);
            acc[t] = __builtin_amdgcn_mfma_f32_16x16x32_bf16(ah, wl, acc[t], 0, 0, 0);
            acc[t] = __builtin_amdgcn_mfma_f32_16x16x32_bf16(al, wh, acc[t], 0, 0, 0);
        }
    }
    __syncthreads();

#pragma unroll
    for (int t = 0; t < 4; ++t) {
        int col = (nt0 + t) * 16 + m;
        float bv = bc[col];
#pragma unroll
        for (int r = 0; r < 4; ++r)
            outb[(quad * 4 + r) * OPAD + col] = acc[t][r] + bv;
    }
    __syncthreads();

    if (tid < MB * NHq) {
        int r = tid >> 3, n = tid & 7;
        float su = 0.f, sd = 0.f;
        for (int d = 0; d < Dq; ++d) {
            float v = outb[r * OPAD + n * Dq + d];
            su += v * upon[n * Dq + d];
            sd += v * down[n * Dq + d];
        }
        uq[(b * NHq + n) * Lq + l0 + r] = su;
        dsv[(b * NHq + n) * Lq + l0 + r] = sd;
    }
    {
        float* dst = ctx_hT + (size_t)(b * Hq + tid) * Lq + l0;
#pragma unroll
        for (int j = 0; j < MB / 4; ++j) {
            float4 o;
            o.x = outb[(4 * j + 0) * OPAD + tid];
            o.y = outb[(4 * j + 1) * OPAD + tid];
            o.z = outb[(4 * j + 2) * OPAD + tid];
            o.w = outb[(4 * j + 3) * OPAD + tid];
            ((float4*)dst)[j] = o;
        }
    }
}

// ---------------- attention: tiled (b, n, 64 l's) per block ----------------
// R12: score phase (cr, t-scores, window dots) moved to MFMA, all D[l][*]
// orientation, bf16 hi/lo 3-term. Softmax redistributed to MFMA C-layout.
// Epilogue MFMA unchanged in structure. 52.7 KB LDS -> 3 blocks/CU, 3 barriers.
__global__ void __launch_bounds__(256, 3) k_attn(
        const float* __restrict__ ctx_hT, const float* __restrict__ types_h,
        const float* __restrict__ types_hT, const float* __restrict__ cross,
        const float* __restrict__ uq, const float* __restrict__ dsv,
        const float* __restrict__ dt, const unsigned char* __restrict__ maskp,
        float* __restrict__ update) {
    int blk = blockIdx.x;
    int lt = blk & 63, n = (blk >> 6) & 7, b = blk >> 9;
    int l0 = lt * TLq;
    int tid = threadIdx.x;
    int g = tid >> 6;          // wave id -> l-group 16g..16g+15
    int lane = tid & 63;
    int Q = lane >> 4, s = lane & 15;
    bool mask_b8 = (maskp[1] != 0);

    __shared__ __align__(16) char smem[53952];
    // persistent-then-aliased layout:
    uint16_t* TT_hi     = (uint16_t*)(smem);            // [64][40]  5120 B
    uint16_t* TT_lo     = (uint16_t*)(smem + 5120);
    uint16_t* chxT_hi   = (uint16_t*)(smem + 10240);    // [80][40]  6400 B
    uint16_t* chxT_lo   = (uint16_t*)(smem + 16640);    //       (ends 23040)
    uint16_t* waT_hi    = (uint16_t*)(smem);            // alias: [64][72] 9216 B
    uint16_t* waT_lo    = (uint16_t*)(smem + 9216);     //       (ends 18432)
    uint16_t* crossT_hi = (uint16_t*)(smem + 23040);    // [32][40]  2560 B
    uint16_t* crossT_lo = (uint16_t*)(smem + 25600);
    uint16_t* crle_hi   = (uint16_t*)(smem + 23040);    // alias: [64][40] 5120 B
    uint16_t* crle_lo   = (uint16_t*)(smem + 28160);    //       (ends 33280)
    uint16_t* waw_hi    = (uint16_t*)(smem + 23040);    // alias: [64][40]
    uint16_t* waw_lo    = (uint16_t*)(smem + 28160);
    uint16_t* chvt_hi   = (uint16_t*)(smem + 33280);    // [32][80]  5120 B
    uint16_t* chvt_lo   = (uint16_t*)(smem + 38400);
    uint16_t* ttvt_hi   = (uint16_t*)(smem + 43520);    // [32][72]  4608 B
    uint16_t* ttvt_lo   = (uint16_t*)(smem + 48128);
    float* uqe   = (float*)(smem + 52736);   // [80]
    float* dsve  = (float*)(smem + 53056);   // [80]  base = l0-16
    float* maskf = (float*)(smem + 53376);   // [80]
    float* dts   = (float*)(smem + 53696);   // [64]  (end 53952)

    // ---------------- phase 0: staging ----------------
    {   // window values ctx_h[d][l0..l0+79] -> chvt [d][w] + chxT [w][d], bf16 hi/lo
        int d_ = tid >> 3, k_ = tid & 7, base = k_ * 10;
        const float* grow = ctx_hT + ((size_t)(b * NHq + n) * Dq + d_) * Lq;
        float cv[10];
        if (l0 <= Lq - 80) {
            const float2* g2 = (const float2*)(grow + l0 + base);
#pragma unroll
            for (int j = 0; j < 5; ++j) { float2 v = g2[j]; cv[2*j] = v.x; cv[2*j+1] = v.y; }
        } else {
#pragma unroll
            for (int m = 0; m < 10; ++m) {
                int gl = l0 + base + m;
                cv[m] = grow[gl >= Lq ? gl - Lq : gl];
            }
        }
        uint16_t hh[10], ll[10];
#pragma unroll
        for (int m = 0; m < 10; ++m) {
            hh[m] = f2bf(cv[m]);
            ll[m] = f2bf(cv[m] - bf2f(hh[m]));
        }
#pragma unroll
        for (int j = 0; j < 5; ++j) {
            *(uint*)&chvt_hi[d_ * 80 + base + 2*j] = (uint)hh[2*j] | ((uint)hh[2*j+1] << 16);
            *(uint*)&chvt_lo[d_ * 80 + base + 2*j] = (uint)ll[2*j] | ((uint)ll[2*j+1] << 16);
        }
#pragma unroll
        for (int m = 0; m < 10; ++m) {
            chxT_hi[(base + m) * 40 + d_] = hh[m];
            chxT_lo[(base + m) * 40 + d_] = ll[m];
        }
    }
    {   // crossT [e][d]
        int d_ = tid >> 3, e4 = (tid & 7) * 4;
        float4 v = ((const float4*)(cross + n * (Dq * Dq)))[tid];
        float vv[4] = {v.x, v.y, v.z, v.w};
#pragma unroll
        for (int j = 0; j < 4; ++j) {
            uint16_t h = f2bf(vv[j]);
            crossT_hi[(e4 + j) * 40 + d_] = h;
            crossT_lo[(e4 + j) * 40 + d_] = f2bf(vv[j] - bf2f(h));
        }
    }
    {   // TT [t][e]
        int t = tid >> 2, c8 = (tid & 3) * 8;
        const float* src = types_h + (size_t)(b * Tq + t) * Hq + n * Dq + c8;
        float4 v0 = *(const float4*)src, v1 = *(const float4*)(src + 4);
        float vv[8] = {v0.x, v0.y, v0.z, v0.w, v1.x, v1.y, v1.z, v1.w};
        uint hp[4], lp[4];
#pragma unroll
        for (int j = 0; j < 4; ++j) {
            uint16_t h0 = f2bf(vv[2*j]), h1 = f2bf(vv[2*j+1]);
            hp[j] = (uint)h0 | ((uint)h1 << 16);
            lp[j] = (uint)f2bf(vv[2*j] - bf2f(h0)) | ((uint)f2bf(vv[2*j+1] - bf2f(h1)) << 16);
        }
        *(uint4*)&TT_hi[t * 40 + c8] = make_uint4(hp[0], hp[1], hp[2], hp[3]);
        *(uint4*)&TT_lo[t * 40 + c8] = make_uint4(lp[0], lp[1], lp[2], lp[3]);
    }
    {   // TTVT [d][t]
        int d_ = tid >> 3, t8 = (tid & 7) * 8;
        const float* src = types_hT + ((size_t)(b * Hq) + n * Dq + d_) * Tq + t8;
        float4 v0 = *(const float4*)src, v1 = *(const float4*)(src + 4);
        float vv[8] = {v0.x, v0.y, v0.z, v0.w, v1.x, v1.y, v1.z, v1.w};
        uint hp[4], lp[4];
#pragma unroll
        for (int j = 0; j < 4; ++j) {
            uint16_t h0 = f2bf(vv[2*j]), h1 = f2bf(vv[2*j+1]);
            hp[j] = (uint)h0 | ((uint)h1 << 16);
            lp[j] = (uint)f2bf(vv[2*j] - bf2f(h0)) | ((uint)f2bf(vv[2*j+1] - bf2f(h1)) << 16);
        }
        *(uint4*)&ttvt_hi[d_ * 72 + t8] = make_uint4(hp[0], hp[1], hp[2], hp[3]);
        *(uint4*)&ttvt_lo[d_ * 72 + t8] = make_uint4(lp[0], lp[1], lp[2], lp[3]);
    }
    if (tid < 80) {
        int gl = l0 + tid;
        int glw = gl >= Lq ? gl - Lq : gl;
        uqe[tid] = uq[(b * NHq + n) * Lq + glw];
        unsigned char mb = mask_b8 ? maskp[b * Lq + glw]
                                   : maskp[(size_t)(b * Lq + glw) * 4];
        maskf[tid] = mb ? 1.f : 0.f;
    } else if (tid >= 96 && tid < 176) {
        int i = tid - 96;
        int gl = l0 - 16 + i;
        int glw = gl < 0 ? gl + Lq : (gl >= Lq ? gl - Lq : gl);
        dsve[i] = dsv[(b * NHq + n) * Lq + glw];
    } else if (tid >= 192) {
        dts[tid - 192] = dt[(b * NHq + n) * Tq + (tid - 192)];
    }
    __syncthreads();    // B1

    // ---------------- P1: cr[l][e] = ctx_h[l] . cross ----------------
    f32x4 cr0 = (f32x4){0.f, 0.f, 0.f, 0.f};
    f32x4 cr1 = (f32x4){0.f, 0.f, 0.f, 0.f};
    {
        short8 axh = *(const short8*)&chxT_hi[(16*g + s) * 40 + 8*Q];
        short8 axl = *(const short8*)&chxT_lo[(16*g + s) * 40 + 8*Q];
        short8 b0h = *(const short8*)&crossT_hi[s * 40 + 8*Q];
        short8 b0l = *(const short8*)&crossT_lo[s * 40 + 8*Q];
        short8 b1h = *(const short8*)&crossT_hi[(16 + s) * 40 + 8*Q];
        short8 b1l = *(const short8*)&crossT_lo[(16 + s) * 40 + 8*Q];
        cr0 = __builtin_amdgcn_mfma_f32_16x16x32_bf16(axh, b0h, cr0, 0, 0, 0);
        cr0 = __builtin_amdgcn_mfma_f32_16x16x32_bf16(axl, b0h, cr0, 0, 0, 0);
        cr0 = __builtin_amdgcn_mfma_f32_16x16x32_bf16(axh, b0l, cr0, 0, 0, 0);
        cr1 = __builtin_amdgcn_mfma_f32_16x16x32_bf16(axh, b1h, cr1, 0, 0, 0);
        cr1 = __builtin_amdgcn_mfma_f32_16x16x32_bf16(axl, b1h, cr1, 0, 0, 0);
        cr1 = __builtin_amdgcn_mfma_f32_16x16x32_bf16(axh, b1l, cr1, 0, 0, 0);
    }
    __syncthreads();    // B2: crossT reads done everywhere before crle overwrite

    // crle [l][e] bf16 hi/lo (lane writes rows of its OWN wave's group only)
#pragma unroll
    for (int r = 0; r < 4; ++r) {
        int row = 16*g + 4*Q + r;
        uint16_t h0 = f2bf(cr0[r]);
        crle_hi[row * 40 + s] = h0;
        crle_lo[row * 40 + s] = f2bf(cr0[r] - bf2f(h0));
        uint16_t h1 = f2bf(cr1[r]);
        crle_hi[row * 40 + 16 + s] = h1;
        crle_lo[row * 40 + 16 + s] = f2bf(cr1[r] - bf2f(h1));
    }
    // (no barrier: each wave reads back only rows it wrote)

    // ---------------- P2 (t-scores) + P3 (window dots) ----------------
    f32x4 p2[4], p3[2];
#pragma unroll
    for (int c = 0; c < 4; ++c) p2[c] = (f32x4){0.f, 0.f, 0.f, 0.f};
#pragma unroll
    for (int t_ = 0; t_ < 2; ++t_) p3[t_] = (f32x4){0.f, 0.f, 0.f, 0.f};
    {
        short8 cah = *(const short8*)&crle_hi[(16*g + s) * 40 + 8*Q];
        short8 cal = *(const short8*)&crle_lo[(16*g + s) * 40 + 8*Q];
#pragma unroll
        for (int c = 0; c < 4; ++c) {
            short8 bh = *(const short8*)&TT_hi[(s + 16*c) * 40 + 8*Q];
            short8 bl = *(const short8*)&TT_lo[(s + 16*c) * 40 + 8*Q];
            p2[c] = __builtin_amdgcn_mfma_f32_16x16x32_bf16(cah, bh, p2[c], 0, 0, 0);
            p2[c] = __builtin_amdgcn_mfma_f32_16x16x32_bf16(cal, bh, p2[c], 0, 0, 0);
            p2[c] = __builtin_amdgcn_mfma_f32_16x16x32_bf16(cah, bl, p2[c], 0, 0, 0);
        }
#pragma unroll
        for (int t_ = 0; t_ < 2; ++t_) {
            short8 bh = *(const short8*)&chxT_hi[(16*g + 16*t_ + s) * 40 + 8*Q];
            short8 bl = *(const short8*)&chxT_lo[(16*g + 16*t_ + s) * 40 + 8*Q];
            p3[t_] = __builtin_amdgcn_mfma_f32_16x16x32_bf16(cah, bh, p3[t_], 0, 0, 0);
            p3[t_] = __builtin_amdgcn_mfma_f32_16x16x32_bf16(cal, bh, p3[t_], 0, 0, 0);
            p3[t_] = __builtin_amdgcn_mfma_f32_16x16x32_bf16(cah, bl, p3[t_], 0, 0, 0);
        }
    }

    // ---------------- softmax (C-layout: lane = col, 4 rows) ----------------
    float uqr[4], cmr[4], dsr[4], dd[4];
    *(float4*)uqr = *(const float4*)&uqe[16*g + 4*Q];
    *(float4*)cmr = *(const float4*)&maskf[16*g + 4*Q];
    *(float4*)dsr = *(const float4*)&dsve[16*g + 4*Q + 16];
#pragma unroll
    for (int r = 0; r < 4; ++r) dd[r] = dsve[16*g + 4*Q + s + r];
    float dtv[4], uw[2], mw[2];
#pragma unroll
    for (int c = 0; c < 4; ++c) dtv[c] = dts[s + 16*c];
#pragma unroll
    for (int t_ = 0; t_ < 2; ++t_) {
        uw[t_] = uqe[16*g + s + 16*t_];
        mw[t_] = maskf[16*g + s + 16*t_];
    }
    // dot_self broadcast: cell (row r, col li=4Q+r) lives in lane 16Q+4Q+r, tile0 reg r
    float dsb[4];
#pragma unroll
    for (int r = 0; r < 4; ++r) dsb[r] = __shfl(p3[0][r], 20*Q + r);

    float stt[4][4], rup[2][4], rdn[4], rdn16[4];
#pragma unroll
    for (int c = 0; c < 4; ++c)
#pragma unroll
        for (int r = 0; r < 4; ++r)
            stt[c][r] = leaky(uqr[r] + dtv[c] + p2[c][r]);
#pragma unroll
    for (int t_ = 0; t_ < 2; ++t_)
#pragma unroll
        for (int r = 0; r < 4; ++r) {
            int u = s + 16*t_ - 4*Q - r;
            bool ok = (u >= 1) && (u <= 16) && (l0 + 16*g + s + 16*t_ < Lq)
                      && (mw[t_] > 0.5f);
            rup[t_][r] = ok ? leaky(uw[t_] + dsr[r] + p3[t_][r]) : MASK_FILL;
        }
#pragma unroll
    for (int r = 0; r < 4; ++r) {
        bool okd = (l0 + 16*g + 4*Q + r + s >= 16) && (cmr[r] > 0.5f);
        rdn[r]   = okd ? leaky(uqr[r] + dd[r] + dsb[r]) : MASK_FILL;
        rdn16[r] = (s == 0 && cmr[r] > 0.5f) ? leaky(uqr[r] + dsr[r] + dsb[r])
                                             : MASK_FILL;
    }

    float mx[4];
#pragma unroll
    for (int r = 0; r < 4; ++r) {
        float m = fmaxf(fmaxf(stt[0][r], stt[1][r]), fmaxf(stt[2][r], stt[3][r]));
        m = fmaxf(m, fmaxf(rup[0][r], rup[1][r]));
        m = fmaxf(m, fmaxf(rdn[r], rdn16[r]));
        mx[r] = m;
    }
#pragma unroll
    for (int msk = 1; msk <= 8; msk <<= 1)
#pragma unroll
        for (int r = 0; r < 4; ++r) mx[r] = fmaxf(mx[r], __shfl_xor(mx[r], msk));

    float sTU[4] = {0.f, 0.f, 0.f, 0.f}, sD[4];
#pragma unroll
    for (int c = 0; c < 4; ++c)
#pragma unroll
        for (int r = 0; r < 4; ++r) {
            stt[c][r] = __expf(stt[c][r] - mx[r]);
            sTU[r] += stt[c][r];
        }
#pragma unroll
    for (int t_ = 0; t_ < 2; ++t_)
#pragma unroll
        for (int r = 0; r < 4; ++r) {
            rup[t_][r] = __expf(rup[t_][r] - mx[r]);
            sTU[r] += rup[t_][r];
        }
#pragma unroll
    for (int r = 0; r < 4; ++r) {
        rdn[r] = __expf(rdn[r] - mx[r]);
        rdn16[r] = __expf(rdn16[r] - mx[r]);
        sD[r] = rdn[r] + rdn16[r];
    }
#pragma unroll
    for (int msk = 1; msk <= 8; msk <<= 1)
#pragma unroll
        for (int r = 0; r < 4; ++r) {
            sTU[r] += __shfl_xor(sTU[r], msk);
            sD[r]  += __shfl_xor(sD[r], msk);
        }
    float inv[4], wself[4];
#pragma unroll
    for (int r = 0; r < 4; ++r) {
        inv[r] = 1.f / (sTU[r] + sD[r]);
        wself[r] = sD[r] * inv[r];
    }

    __syncthreads();    // B4: all TT/chxT/crle reads done; alias as waT/waw

    // ---------------- weight writes (bf16 hi/lo) ----------------
#pragma unroll
    for (int r = 0; r < 4; ++r) {
        int row = 16*g + 4*Q + r;
#pragma unroll
        for (int c = 0; c < 4; ++c) {
            float v = stt[c][r] * inv[r];
            uint16_t h = f2bf(v);
            waT_hi[row * 72 + s + 16*c] = h;
            waT_lo[row * 72 + s + 16*c] = f2bf(v - bf2f(h));
        }
#pragma unroll
        for (int t_ = 0; t_ < 2; ++t_) {
            int u = s + 16*t_ - 4*Q - r;
            float v = (u == 0) ? wself[r]
                    : ((u >= 1 && u <= 16) ? rup[t_][r] * inv[r] : 0.f);
            uint16_t h = f2bf(v);
            waw_hi[row * 40 + s + 16*t_] = h;
            waw_lo[row * 40 + s + 16*t_] = f2bf(v - bf2f(h));
        }
    }
    // (no barrier: epilogue reads only rows this wave wrote)

    // ---------------- epilogue MFMAs: updT[d][l] ----------------
    f32x4 a0 = (f32x4){0.f, 0.f, 0.f, 0.f};
    f32x4 a1 = (f32x4){0.f, 0.f, 0.f, 0.f};
#pragma unroll
    for (int ks = 0; ks < 2; ++ks) {
        short8 bh = *(const short8*)&waT_hi[(16*g + s) * 72 + 32*ks + 8*Q];
        short8 bl = *(const short8*)&waT_lo[(16*g + s) * 72 + 32*ks + 8*Q];
        short8 t0h = *(const short8*)&ttvt_hi[s * 72 + 32*ks + 8*Q];
        short8 t0l = *(const short8*)&ttvt_lo[s * 72 + 32*ks + 8*Q];
        short8 t1h = *(const short8*)&ttvt_hi[(16 + s) * 72 + 32*ks + 8*Q];
        short8 t1l = *(const short8*)&ttvt_lo[(16 + s) * 72 + 32*ks + 8*Q];
        a0 = __builtin_amdgcn_mfma_f32_16x16x32_bf16(t0h, bh, a0, 0, 0, 0);
        a0 = __builtin_amdgcn_mfma_f32_16x16x32_bf16(t0l, bh, a0, 0, 0, 0);
        a0 = __builtin_amdgcn_mfma_f32_16x16x32_bf16(t0h, bl, a0, 0, 0, 0);
        a1 = __builtin_amdgcn_mfma_f32_16x16x32_bf16(t1h, bh, a1, 0, 0, 0);
        a1 = __builtin_amdgcn_mfma_f32_16x16x32_bf16(t1l, bh, a1, 0, 0, 0);
        a1 = __builtin_amdgcn_mfma_f32_16x16x32_bf16(t1h, bl, a1, 0, 0, 0);
    }
    {
        short8 wbh = *(const short8*)&waw_hi[(16*g + s) * 40 + 8*Q];
        short8 wbl = *(const short8*)&waw_lo[(16*g + s) * 40 + 8*Q];
        short8 c0h = *(const short8*)&chvt_hi[s * 80 + 16*g + 8*Q];
        short8 c0l = *(const short8*)&chvt_lo[s * 80 + 16*g + 8*Q];
        short8 c1h = *(const short8*)&chvt_hi[(16 + s) * 80 + 16*g + 8*Q];
        short8 c1l = *(const short8*)&chvt_lo[(16 + s) * 80 + 16*g + 8*Q];
        a0 = __builtin_amdgcn_mfma_f32_16x16x32_bf16(c0h, wbh, a0, 0, 0, 0);
        a0 = __builtin_amdgcn_mfma_f32_16x16x32_bf16(c0l, wbh, a0, 0, 0, 0);
        a0 = __builtin_amdgcn_mfma_f32_16x16x32_bf16(c0h, wbl, a0, 0, 0, 0);
        a1 = __builtin_amdgcn_mfma_f32_16x16x32_bf16(c1h, wbh, a1, 0, 0, 0);
        a1 = __builtin_amdgcn_mfma_f32_16x16x32_bf16(c1l, wbh, a1, 0, 0, 0);
        a1 = __builtin_amdgcn_mfma_f32_16x16x32_bf16(c1h, wbl, a1, 0, 0, 0);
    }

    // C write: updT[d][l] -> update[b][l][n*32+d]
    {
        int lcol = l0 + 16*g + s;
        float* dst = update + (size_t)(b * Lq + lcol) * Hq + n * Dq + 4*Q;
        *(float4*)dst        = make_float4(a0[0], a0[1], a0[2], a0[3]);
        *(float4*)(dst + 16) = make_float4(a1[0], a1[1], a1[2], a1[3]);
    }
}

// ---------------- output GEMM via MFMA + tanh ----------------
__global__ void __launch_bounds__(256) k_out(
        const float* __restrict__ update, const float* __restrict__ ctx,
        const uint16_t* __restrict__ wp_hi, const uint16_t* __restrict__ wp_lo,
        const float* __restrict__ bo, float* __restrict__ out) {
    int row0 = blockIdx.x * MB;
    int tid = threadIdx.x;
    int w = tid >> 6, l = tid & 63;
    __shared__ __align__(16) char smem_raw[MB * APAD * 4];
    uint16_t* a_hi = (uint16_t*)smem_raw;
    uint16_t* a_lo = a_hi + MB * APAD;

    {
        const float4* s0 = (const float4*)(update + (size_t)row0 * Hq);
        const float4* s1 = (const float4*)(ctx + (size_t)row0 * Hq);
#pragma unroll
        for (int j = 0; j < 4; ++j) {
            int f = tid + j * 256;
            int r = f >> 6, cg = f & 63;
            float4 a = s0[f], bv = s1[f];
            float4 v; v.x = a.x + bv.x; v.y = a.y + bv.y;
            v.z = a.z + bv.z; v.w = a.w + bv.w;
            uint16_t h0 = f2bf(v.x), h1 = f2bf(v.y), h2 = f2bf(v.z), h3 = f2bf(v.w);
            ushort4 hh = {h0, h1, h2, h3};
            ushort4 ll = {f2bf(v.x - bf2f(h0)), f2bf(v.y - bf2f(h1)),
                          f2bf(v.z - bf2f(h2)), f2bf(v.w - bf2f(h3))};
            *(ushort4*)&a_hi[r * APAD + cg * 4] = hh;
            *(ushort4*)&a_lo[r * APAD + cg * 4] = ll;
        }
    }
    __syncthreads();

    int nt0 = w * 4;
    int m = l & 15, quad = l >> 4;
    f32x4 acc[4];
#pragma unroll
    for (int t = 0; t < 4; ++t) acc[t] = (f32x4){0.f, 0.f, 0.f, 0.f};
#pragma unroll
    for (int kc = 0; kc < 8; ++kc) {
        short8 ah = *(const short8*)&a_hi[m * APAD + kc * 32 + quad * 8];
        short8 al = *(const short8*)&a_lo[m * APAD + kc * 32 + quad * 8];
#pragma unroll
        for (int t = 0; t < 4; ++t) {
            int fragi = (nt0 + t) * 8 + kc;
            short8 wh = *(const short8*)&wp_hi[fragi * 512 + l * 8];
            short8 wl = *(const short8*)&wp_lo[fragi * 512 + l * 8];
            acc[t] = __builtin_amdgcn_mfma_f32_16x16x32_bf16(ah, wh, acc[t], 0, 0, 0);
            acc[t] = __builtin_amdgcn_mfma_f32_16x16x32_bf16(ah, wl, acc[t], 0, 0, 0);
            acc[t] = __builtin_amdgcn_mfma_f32_16x16x32_bf16(al, wh, acc[t], 0, 0, 0);
        }
    }
#pragma unroll
    for (int t = 0; t < 4; ++t) {
        int col = (nt0 + t) * 16 + m;
        float bv = bo[col];
#pragma unroll
        for (int r = 0; r < 4; ++r)
            out[(size_t)(row0 + quad * 4 + r) * Hq + col] = tanhf(acc[t][r] + bv);
    }
}

extern "C" void kernel_launch(void* const* d_in, const int* in_sizes, int n_in,
                              void* d_out, int out_size, void* d_ws, size_t ws_size,
                              hipStream_t stream) {
    const float* context   = (const float*)d_in[0];
    const float* types     = (const float*)d_in[1];
    const unsigned char* cmask = (const unsigned char*)d_in[2];
    const float* W_types   = (const float*)d_in[3];
    const float* b_types   = (const float*)d_in[4];
    const float* W_context = (const float*)d_in[5];
    const float* b_context = (const float*)d_in[6];
    const float* upon      = (const float*)d_in[7];
    const float* down      = (const float*)d_in[8];
    const float* cross     = (const float*)d_in[9];
    const float* W_out     = (const float*)d_in[10];
    const float* b_out     = (const float*)d_in[11];
    float* out = (float*)d_out;
    float* ws  = (float*)d_ws;

    float* ctx_hT   = ws;             // [b][n][d][l]
    float* update   = ws + 4194304;
    uint16_t* wcp_hi = (uint16_t*)(ws + 8388608);
    uint16_t* wcp_lo = wcp_hi + 65536;
    uint16_t* wop_hi = wcp_hi + 131072;
    uint16_t* wop_lo = wcp_hi + 196608;

    float* types_h  = out;            // 65536   [b][t][h]
    float* types_hT = out + 65536;    // 65536   [b][n][d][t]
    float* down_t   = out + 131072;   // 2048
    float* uqp      = out + 133120;   // 131072
    float* dsvp     = out + 264192;   // 131072

    k_prep<<<128 + Bq * Tq, 256, 0, stream>>>(W_context, W_out,
                                              wcp_hi, wcp_lo, wop_hi, wop_lo,
                                              types, W_types, b_types, down,
                                              types_h, types_hT, down_t);
    k_ctx<<<Bq * Lq / MB, 256, 0, stream>>>(context, wcp_hi, wcp_lo, b_context,
                                            upon, down, ctx_hT, uqp, dsvp);
    k_attn<<<Bq * NHq * (Lq / TLq), 256, 0, stream>>>(ctx_hT, types_h, types_hT, cross,
                                                      uqp, dsvp, down_t, cmask, update);
    k_out<<<Bq * Lq / MB, 256, 0, stream>>>(update, context, wop_hi, wop_lo, b_out, out);
}